// Round 2
// baseline (38.351 us; speedup 1.0000x reference)
//
#include <hip/hip_runtime.h>

// Problem constants (fixed by setup_inputs): B=8, L=16384, H=2, BLOCK=128, VOCAB=32000
#define NB        8
#define LLEN      16384
#define NHEAD     2
#define BLOCKSZ   128
#define VOCAB     32000
#define NBLK      (LLEN / BLOCKSZ)                  // 128
#define TOKS_PER_CHUNK (BLOCKSZ * NHEAD)            // 256
#define NT_COLS   (TOKS_PER_CHUNK + LLEN * NHEAD)   // 33024 per batch row
#define NT_TOTAL  (NB * NT_COLS)                    // 264192
#define CAT_TOTAL (NB * TOKS_PER_CHUNK)             // 2048
#define HIST_OFF  (NT_TOTAL + CAT_TOTAL)            // 266240

typedef float f32x4 __attribute__((ext_vector_type(4)));

// One workgroup per (b, n) chunk. Does EVERYTHING for that chunk:
//  - new_tokens flat part (256 floats) + cat part (2 floats) + cat_ids (2 floats)
//  - per-chunk histogram: counts in LDS (u16), then ONE streaming global pass
//    (no global-store drain before a barrier, no scatter tail).
__global__ __launch_bounds__(256) void fused_kernel(const int* __restrict__ tokens,
                                                    float* __restrict__ out) {
    __shared__ int toks[TOKS_PER_CHUNK];              // 1 KB
    __shared__ unsigned short cnt[VOCAB];             // 62.5 KB

    const int tid = threadIdx.x;
    const int chunk = blockIdx.x;                     // b*128 + n
    const int b = chunk >> 7;
    const int n = chunk & 127;

    // tokens[b, n*128 .. n*128+127, 0..1] = 256 contiguous ints at chunk*256
    toks[tid] = tokens[(size_t)chunk * TOKS_PER_CHUNK + tid];

    // zero LDS counts: 64000 B = 4000 uint4
    {
        uint4 z = make_uint4(0u, 0u, 0u, 0u);
        uint4* c4 = reinterpret_cast<uint4*>(cnt);
        #pragma unroll
        for (int k = 0; k < 16; ++k) {                // 16*256 = 4096 >= 4000
            int i = tid + k * 256;
            if (i < VOCAB * 2 / 16) c4[i] = z;
        }
    }
    __syncthreads();   // LDS-only wait (lgkmcnt), fast

    const int v = toks[tid];
    const float fv = (float)v;

    // token outputs (independent of the histogram)
    out[(size_t)b * NT_COLS + TOKS_PER_CHUNK + n * BLOCKSZ * NHEAD + tid] = fv;
    if (tid < NHEAD) {
        // toks[0..1] are tokens[b, n*128, h] -> cat entries for this chunk
        out[(size_t)b * NT_COLS + n * NHEAD + tid] = fv;
        out[(size_t)NT_TOTAL + b * TOKS_PER_CHUNK + n * NHEAD + tid] = fv;
    }

    // duplicate scan over the 256 tokens (LDS broadcast reads, conflict-free)
    int c = 0, first = -1;
    #pragma unroll 8
    for (int j = 0; j < TOKS_PER_CHUNK; ++j) {
        const int u = toks[j];
        c += (u == v);
        if (u == v && first < 0) first = j;
    }
    if (first == tid) cnt[v] = (unsigned short)c;   // unique v per first-thread; b16 LDS write
    __syncthreads();   // LDS-only wait again

    // ONE streaming pass: LDS u16 x4 -> float4 nontemporal store
    float* __restrict__ row = out + HIST_OFF + (size_t)chunk * VOCAB;
    const uint2* __restrict__ c2 = reinterpret_cast<const uint2*>(cnt);
    #pragma unroll
    for (int k = 0; k < 32; ++k) {                    // 32*256 = 8192 >= 8000
        int i = tid + k * 256;
        if (i < VOCAB / 4) {
            uint2 w = c2[i];
            f32x4 f;
            f.x = (float)(w.x & 0xFFFFu);
            f.y = (float)(w.x >> 16);
            f.z = (float)(w.y & 0xFFFFu);
            f.w = (float)(w.y >> 16);
            __builtin_nontemporal_store(f, reinterpret_cast<f32x4*>(row) + i);
        }
    }
}

extern "C" void kernel_launch(void* const* d_in, const int* in_sizes, int n_in,
                              void* d_out, int out_size, void* d_ws, size_t ws_size,
                              hipStream_t stream) {
    const int* tokens = (const int*)d_in[0];
    float* out = (float*)d_out;
    fused_kernel<<<NB * NBLK, 256, 0, stream>>>(tokens, out);
}